// Round 3
// baseline (637.243 us; speedup 1.0000x reference)
//
#include <hip/hip_runtime.h>
#include <cstddef>

// ---------------------------------------------------------------------------
// SO2_Linear fp32 baseline (audited r1, re-verified r2).
// Pipeline:
//   1. wigner_k      : per-edge D1 (3x3), D2 (5x5) -> ws
//   2. build_mats    : expand W0/W1/W2 into dense M0(384x256), M1(512x512),
//                      M2(256x256) + b0 -> ws
//   3. rotate_gather : x row -> D^T-rotated, gathered U row (1024) -> ws
//   4. gemm_k        : 3 sections of C = A @ M^T (+bias) -> d_out (packed V)
//   5. rotate_back   : packed V row -> D-rotated final layout, in-place d_out
//
// U layout (1024):  [ l1mid(128) | l2mid(128) | l1 m1-pairs(256) |
//                     l2 m1-pairs(256) | l2 m2-pairs ch0-63(128) | ch64-127(128) ]
// V layout (1152):  [ l0out(128) | l1mid(128) | l2mid(128) | l1 m1-pairs(256) |
//                     l2 m1-pairs(256) | l2 m2 ch0-63(128) | ch64-127(128) ]
// ---------------------------------------------------------------------------

__device__ __forceinline__ void mm3(const float* A, const float* B, float* C) {
#pragma unroll
  for (int i = 0; i < 3; ++i)
#pragma unroll
    for (int j = 0; j < 3; ++j)
      C[i*3+j] = fmaf(A[i*3+0], B[0*3+j], fmaf(A[i*3+1], B[1*3+j], A[i*3+2]*B[2*3+j]));
}

__device__ __forceinline__ void mm5(const float* A, const float* B, float* C) {
#pragma unroll
  for (int i = 0; i < 5; ++i)
#pragma unroll
    for (int j = 0; j < 5; ++j) {
      float s = 0.f;
#pragma unroll
      for (int k = 0; k < 5; ++k) s = fmaf(A[i*5+k], B[k*5+j], s);
      C[i*5+j] = s;
    }
}

__global__ __launch_bounds__(256) void wigner_k(const float* __restrict__ R,
                                                float* __restrict__ D1buf,
                                                float* __restrict__ D2buf, int n) {
  int e = blockIdx.x*256 + threadIdx.x;
  if (e >= n) return;
  float r0 = R[3*e+0], r1 = R[3*e+1], r2 = R[3*e+2];
  // v = R[[1,2,0]], normalized
  float v0 = r1, v1 = r2, v2 = r0;
  float nrm = fmaxf(sqrtf(v0*v0 + v1*v1 + v2*v2), 1e-12f);
  float inv = 1.0f/nrm;
  v0 *= inv; v1 *= inv; v2 *= inv;

  // beta = acos(clip(v1)): cb = clip(v1), sb = sqrt(1-cb^2) >= 0
  float cb = fminf(fmaxf(v1, -1.f), 1.f);
  float sb = sqrtf(fmaxf(1.f - cb*cb, 0.f));
  // alpha = atan2(v0, v2): ca = v2/h, sa = v0/h  (atan2(0,0)=0 -> ca=1,sa=0)
  float h = sqrtf(v0*v0 + v2*v2);
  float ca, sa;
  if (h > 1e-20f) { float ih = 1.f/h; ca = v2*ih; sa = v0*ih; }
  else            { ca = 1.f; sa = 0.f; }

  // l=1: D1 = Za @ J1 @ Zb @ J1
  {
    float Za[9] = {ca,0,sa, 0,1,0, -sa,0,ca};
    float Zb[9] = {cb,0,sb, 0,1,0, -sb,0,cb};
    const float J1[9] = {0,1,0, 1,0,0, 0,0,-1};
    float T[9], T2[9], D1[9];
    mm3(Zb, J1, T);
    mm3(J1, T, T2);
    mm3(Za, T2, D1);
#pragma unroll
    for (int i = 0; i < 9; ++i) D1buf[(size_t)e*9 + i] = D1[i];
  }
  // l=2
  {
    float c2a = ca*ca - sa*sa, s2a = 2.f*ca*sa;
    float c2b = cb*cb - sb*sb, s2b = 2.f*cb*sb;
    float Za2[25] = {
      c2a, 0,   0, 0,   s2a,
      0,   ca,  0, sa,  0,
      0,   0,   1, 0,   0,
      0,  -sa,  0, ca,  0,
     -s2a, 0,   0, 0,   c2a};
    float Zb2[25] = {
      c2b, 0,   0, 0,   s2b,
      0,   cb,  0, sb,  0,
      0,   0,   1, 0,   0,
      0,  -sb,  0, cb,  0,
     -s2b, 0,   0, 0,   c2b};
    const float S3 = 0.8660254037844386f;
    const float J2[25] = {
      0, 0, 0,    -1, 0,
      0, 1, 0,     0, 0,
      0, 0, -0.5f, 0, -S3,
     -1, 0, 0,     0, 0,
      0, 0, -S3,   0, 0.5f};
    float T[25], T2[25], D2[25];
    mm5(Zb2, J2, T);
    mm5(J2, T, T2);
    mm5(Za2, T2, D2);
#pragma unroll
    for (int i = 0; i < 25; ++i) D2buf[(size_t)e*25 + i] = D2[i];
  }
}

// Expand weights into dense per-m matrices (row-major N x K).
__global__ __launch_bounds__(256) void build_mats(const float* __restrict__ W0,
                                                  const float* __restrict__ b0,
                                                  const float* __restrict__ W1,
                                                  const float* __restrict__ W2,
                                                  float* __restrict__ M0,
                                                  float* __restrict__ B0,
                                                  float* __restrict__ M1,
                                                  float* __restrict__ M2) {
  int i = blockIdx.x*256 + threadIdx.x;
  if (i < 98304) {                       // M0: 384 x 256 = W0[:,128:384]
    int k = i >> 8, j = i & 255;
    M0[i] = W0[k*384 + 128 + j];
  } else if (i < 98688) {                // B0: 384
    B0[i - 98304] = b0[i - 98304];
  } else if (i < 360832) {               // M1: 512 x 512 = [[Wa,-Wb],[Wb,Wa]]
    int idx = i - 98688;
    int k = idx >> 9, j = idx & 511;
    float val;
    if (k < 256) val = (j < 256) ? W1[k*256 + j] : -W1[(k+256)*256 + (j-256)];
    else         val = (j < 256) ? W1[k*256 + j] :  W1[(k-256)*256 + (j-256)];
    M1[idx] = val;
  } else if (i < 426368) {               // M2: 256 x 256 = [[Wa,-Wb],[Wb,Wa]]
    int idx = i - 360832;
    int k = idx >> 8, j = idx & 255;
    float val;
    if (k < 128) val = (j < 128) ? W2[k*128 + j] : -W2[(k+128)*128 + (j-128)];
    else         val = (j < 128) ? W2[k*128 + j] :  W2[(k-128)*128 + (j-128)];
    M2[idx] = val;
  }
}

// One wave per edge: rotate by D^T and gather into U row layout.
__global__ __launch_bounds__(256) void rotate_gather(const float* __restrict__ x,
                                                     const float* __restrict__ D1buf,
                                                     const float* __restrict__ D2buf,
                                                     float* __restrict__ U, int n) {
  __shared__ float xs[4][1152];
  __shared__ float us[4][1024];
  const int w = threadIdx.x >> 6;
  const int lane = threadIdx.x & 63;
  const int e = blockIdx.x*4 + w;

  // stage x row (1152 floats = 288 float4)
  const float4* xr = (const float4*)(x + (size_t)e*1152);
  float4* xsw = (float4*)xs[w];
#pragma unroll
  for (int i = 0; i < 4; ++i) xsw[lane + i*64] = xr[lane + i*64];
  if (lane < 32) xsw[lane + 256] = xr[lane + 256];

  // per-edge D (wave-uniform loads, L2-cached)
  float d1[9], d2[25];
#pragma unroll
  for (int i = 0; i < 9; ++i) d1[i] = D1buf[(size_t)e*9 + i];
#pragma unroll
  for (int i = 0; i < 25; ++i) d2[i] = D2buf[(size_t)e*25 + i];

  __syncthreads();

#pragma unroll
  for (int h = 0; h < 2; ++h) {
    int c = lane + 64*h;
    // l=1 channel c: b = x[128+3c .. +2], r = D1^T b  (r_i = sum_j D1[j,i] b_j)
    float b0 = xs[w][128 + 3*c + 0];
    float b1 = xs[w][128 + 3*c + 1];
    float b2 = xs[w][128 + 3*c + 2];
    float r0 = fmaf(d1[0], b0, fmaf(d1[3], b1, d1[6]*b2));
    float r1 = fmaf(d1[1], b0, fmaf(d1[4], b1, d1[7]*b2));
    float r2 = fmaf(d1[2], b0, fmaf(d1[5], b1, d1[8]*b2));
    us[w][c]             = r1;  // l1 mid
    us[w][256 + 2*c]     = r0;  // l1 m1 minus
    us[w][256 + 2*c + 1] = r2;  // l1 m1 plus

    // l=2 channel c: q = x[512+5c .. +4], rr = D2^T q
    float q0 = xs[w][512 + 5*c + 0];
    float q1 = xs[w][512 + 5*c + 1];
    float q2 = xs[w][512 + 5*c + 2];
    float q3 = xs[w][512 + 5*c + 3];
    float q4 = xs[w][512 + 5*c + 4];
    float rr[5];
#pragma unroll
    for (int i = 0; i < 5; ++i)
      rr[i] = fmaf(d2[0*5+i], q0, fmaf(d2[1*5+i], q1, fmaf(d2[2*5+i], q2,
               fmaf(d2[3*5+i], q3, d2[4*5+i]*q4))));
    us[w][128 + c]       = rr[2];  // l2 mid
    us[w][512 + 2*c]     = rr[1];  // l2 m1 minus
    us[w][512 + 2*c + 1] = rr[3];  // l2 m1 plus
    if (c < 64) {
      us[w][768 + 2*c]     = rr[0];  // l2 m2, channels 0-63
      us[w][768 + 2*c + 1] = rr[4];
    } else {
      us[w][896 + 2*(c-64)]     = rr[0];  // channels 64-127
      us[w][896 + 2*(c-64) + 1] = rr[4];
    }
  }
  __syncthreads();

  float4* Ur = (float4*)(U + (size_t)e*1024);
  const float4* usw = (const float4*)us[w];
#pragma unroll
  for (int i = 0; i < 4; ++i) Ur[lane + i*64] = usw[lane + i*64];
}

// Tiled fp32 GEMM: C section = A[n x K] @ M^T (+bias) into packed V (d_out).
// blockIdx.y in [0,9): 3 col-tiles m0, 4 m1, 2 m2. Tile 128x128, 8x8/thread.
__global__ __launch_bounds__(256) void gemm_k(const float* __restrict__ U,
                                              const float* __restrict__ M0,
                                              const float* __restrict__ B0,
                                              const float* __restrict__ M1,
                                              const float* __restrict__ M2,
                                              float* __restrict__ C, int n) {
  const int y = blockIdx.y;
  int K, Aoff, Coff, colTile;
  const float* Mp;
  const float* bias = nullptr;
  if (y < 3)      { K = 256; Aoff = 0;   Coff = 0;   colTile = y;     Mp = M0; bias = B0; }
  else if (y < 7) { K = 512; Aoff = 256; Coff = 384; colTile = y - 3; Mp = M1; }
  else            { K = 256; Aoff = 768; Coff = 896; colTile = y - 7; Mp = M2; }
  const int colBase = colTile * 128;
  const int rowBase = blockIdx.x * 128;

  __shared__ float As[16][132];
  __shared__ float Bs[16][132];

  const int t = threadIdx.x;
  const int tx = t & 15, ty = t >> 4;

  const float* Ap = U + (size_t)rowBase * 1024 + Aoff;
  const float* Bp = Mp + (size_t)colBase * K;

  float acc[8][8];
#pragma unroll
  for (int i = 0; i < 8; ++i)
#pragma unroll
    for (int j = 0; j < 8; ++j) acc[i][j] = 0.f;

  for (int kk = 0; kk < K; kk += 16) {
#pragma unroll
    for (int i = 0; i < 8; ++i) {
      int r = ty + i*16;
      As[tx][r] = Ap[(size_t)r*1024 + kk + tx];
      Bs[tx][r] = Bp[(size_t)r*K   + kk + tx];
    }
    __syncthreads();
#pragma unroll
    for (int k = 0; k < 16; ++k) {
      const float4 a0  = *(const float4*)&As[k][ty*4];
      const float4 a1  = *(const float4*)&As[k][64 + ty*4];
      const float4 bb0 = *(const float4*)&Bs[k][tx*4];
      const float4 bb1 = *(const float4*)&Bs[k][64 + tx*4];
      float av[8] = {a0.x,a0.y,a0.z,a0.w, a1.x,a1.y,a1.z,a1.w};
      float bv[8] = {bb0.x,bb0.y,bb0.z,bb0.w, bb1.x,bb1.y,bb1.z,bb1.w};
#pragma unroll
      for (int i = 0; i < 8; ++i)
#pragma unroll
        for (int j = 0; j < 8; ++j)
          acc[i][j] = fmaf(av[i], bv[j], acc[i][j]);
    }
    __syncthreads();
  }

#pragma unroll
  for (int ih = 0; ih < 2; ++ih)
#pragma unroll
    for (int i2 = 0; i2 < 4; ++i2) {
      int r = rowBase + ih*64 + ty*4 + i2;
      float* crow = C + (size_t)r*1152 + Coff + colBase;
#pragma unroll
      for (int jh = 0; jh < 2; ++jh) {
        int colLoc = jh*64 + tx*4;
        float4 v;
        v.x = acc[ih*4+i2][jh*4+0];
        v.y = acc[ih*4+i2][jh*4+1];
        v.z = acc[ih*4+i2][jh*4+2];
        v.w = acc[ih*4+i2][jh*4+3];
        if (bias) {
          v.x += bias[colBase + colLoc + 0];
          v.y += bias[colBase + colLoc + 1];
          v.z += bias[colBase + colLoc + 2];
          v.w += bias[colBase + colLoc + 3];
        }
        *(float4*)(crow + colLoc) = v;
      }
    }
}

// One wave per edge: packed V row -> rotate by D -> final layout. In-place d_out.
__global__ __launch_bounds__(256) void rotate_back(float* __restrict__ out,
                                                   const float* __restrict__ D1buf,
                                                   const float* __restrict__ D2buf, int n) {
  __shared__ float vs[4][1152];
  __shared__ float fs[4][1152];
  const int w = threadIdx.x >> 6;
  const int lane = threadIdx.x & 63;
  const int e = blockIdx.x*4 + w;

  const float4* vr = (const float4*)(out + (size_t)e*1152);
  float4* vsw = (float4*)vs[w];
#pragma unroll
  for (int i = 0; i < 4; ++i) vsw[lane + i*64] = vr[lane + i*64];
  if (lane < 32) vsw[lane + 256] = vr[lane + 256];

  float d1[9], d2[25];
#pragma unroll
  for (int i = 0; i < 9; ++i) d1[i] = D1buf[(size_t)e*9 + i];
#pragma unroll
  for (int i = 0; i < 25; ++i) d2[i] = D2buf[(size_t)e*25 + i];

  __syncthreads();

  // l=0 passthrough (V cols 0..127)
  fs[w][lane]      = vs[w][lane];
  fs[w][64 + lane] = vs[w][64 + lane];

#pragma unroll
  for (int h = 0; h < 2; ++h) {
    int c = lane + 64*h;
    // l=1: pre-rotation vec = [m1-minus, mid, m1-plus]; o_i = sum_j D1[i,j] p_j
    float p0 = vs[w][384 + 2*c];
    float p1 = vs[w][128 + c];
    float p2 = vs[w][384 + 2*c + 1];
    fs[w][128 + 3*c + 0] = fmaf(d1[0], p0, fmaf(d1[1], p1, d1[2]*p2));
    fs[w][128 + 3*c + 1] = fmaf(d1[3], p0, fmaf(d1[4], p1, d1[5]*p2));
    fs[w][128 + 3*c + 2] = fmaf(d1[6], p0, fmaf(d1[7], p1, d1[8]*p2));

    // l=2: vec = [m2-minus, m1-minus, mid, m1-plus, m2-plus]
    float q0, q4;
    if (c < 64) { q0 = vs[w][896 + 2*c];        q4 = vs[w][896 + 2*c + 1]; }
    else        { q0 = vs[w][1024 + 2*(c-64)];  q4 = vs[w][1024 + 2*(c-64) + 1]; }
    float q1 = vs[w][640 + 2*c];
    float q2 = vs[w][256 + c];
    float q3 = vs[w][640 + 2*c + 1];
#pragma unroll
    for (int i = 0; i < 5; ++i)
      fs[w][512 + 5*c + i] = fmaf(d2[i*5+0], q0, fmaf(d2[i*5+1], q1, fmaf(d2[i*5+2], q2,
                              fmaf(d2[i*5+3], q3, d2[i*5+4]*q4))));
  }
  __syncthreads();

  float4* orow = (float4*)(out + (size_t)e*1152);
  const float4* fsw = (const float4*)fs[w];
#pragma unroll
  for (int i = 0; i < 4; ++i) orow[lane + i*64] = fsw[lane + i*64];
  if (lane < 32) orow[lane + 256] = fsw[lane + 256];
}

extern "C" void kernel_launch(void* const* d_in, const int* in_sizes, int n_in,
                              void* d_out, int out_size, void* d_ws, size_t ws_size,
                              hipStream_t stream) {
  const float* x  = (const float*)d_in[0];
  const float* R  = (const float*)d_in[1];
  const float* W0 = (const float*)d_in[2];
  const float* b0 = (const float*)d_in[3];
  const float* W1 = (const float*)d_in[4];
  const float* W2 = (const float*)d_in[5];
  float* out = (float*)d_out;

  const int n = in_sizes[0] / 1152;   // 32768

  // workspace layout (floats): U is the big chunk (134 MB); total ~141 MB
  float* ws = (float*)d_ws;
  float* U     = ws;                              // n*1024
  float* D1buf = U + (size_t)n*1024;              // n*9
  float* D2buf = D1buf + (size_t)n*9;             // n*25
  float* M0    = D2buf + (size_t)n*25;            // 98304
  float* B0    = M0 + 98304;                      // 384
  float* M1    = B0 + 384;                        // 262144
  float* M2    = M1 + 262144;                     // 65536

  wigner_k<<<(n + 255)/256, 256, 0, stream>>>(R, D1buf, D2buf, n);
  build_mats<<<(426368 + 255)/256, 256, 0, stream>>>(W0, b0, W1, W2, M0, B0, M1, M2);
  rotate_gather<<<n/4, 256, 0, stream>>>(x, D1buf, D2buf, U, n);
  dim3 ggrid(n/128, 9);
  gemm_k<<<ggrid, 256, 0, stream>>>(U, M0, B0, M1, M2, out, n);
  rotate_back<<<n/4, 256, 0, stream>>>(out, D1buf, D2buf, n);
}

// Round 4
// 383.655 us; speedup vs baseline: 1.6610x; 1.6610x over previous
//
#include <hip/hip_runtime.h>
#include <cstddef>
#include <cstdint>

// ---------------------------------------------------------------------------
// SO2_Linear, r3: fp16-MFMA GEMM stage (reference slack 0.0156 >> fp16 noise).
//   1. wigner_k      : per-edge D1 (3x3), D2 (5x5) -> ws (f32)
//   2. build_mats    : expand W0/W1/W2 -> M0h(384x256), M1h(512x512),
//                      M2h(256x256) fp16 + B0 f32 -> ws
//   3. rotate_gather : x row -> D^T-rotated, gathered U row (1024) fp16 -> ws
//   4. gemm_mfma     : 3 sections C = A @ M^T (+bias), 16x16x32 f16 MFMA -> d_out
//   5. rotate_back   : packed V row -> D-rotated final layout, in-place (f32)
// ---------------------------------------------------------------------------

typedef _Float16 f16x8 __attribute__((ext_vector_type(8)));
typedef _Float16 f16x2 __attribute__((ext_vector_type(2)));
typedef float    f32x4 __attribute__((ext_vector_type(4)));

#define AS1 __attribute__((address_space(1)))
#define AS3 __attribute__((address_space(3)))

__device__ __forceinline__ void mm3(const float* A, const float* B, float* C) {
#pragma unroll
  for (int i = 0; i < 3; ++i)
#pragma unroll
    for (int j = 0; j < 3; ++j)
      C[i*3+j] = fmaf(A[i*3+0], B[0*3+j], fmaf(A[i*3+1], B[1*3+j], A[i*3+2]*B[2*3+j]));
}

__device__ __forceinline__ void mm5(const float* A, const float* B, float* C) {
#pragma unroll
  for (int i = 0; i < 5; ++i)
#pragma unroll
    for (int j = 0; j < 5; ++j) {
      float s = 0.f;
#pragma unroll
      for (int k = 0; k < 5; ++k) s = fmaf(A[i*5+k], B[k*5+j], s);
      C[i*5+j] = s;
    }
}

__global__ __launch_bounds__(256) void wigner_k(const float* __restrict__ R,
                                                float* __restrict__ D1buf,
                                                float* __restrict__ D2buf, int n) {
  int e = blockIdx.x*256 + threadIdx.x;
  if (e >= n) return;
  float r0 = R[3*e+0], r1 = R[3*e+1], r2 = R[3*e+2];
  float v0 = r1, v1 = r2, v2 = r0;          // v = R[[1,2,0]]
  float nrm = fmaxf(sqrtf(v0*v0 + v1*v1 + v2*v2), 1e-12f);
  float inv = 1.0f/nrm;
  v0 *= inv; v1 *= inv; v2 *= inv;

  float cb = fminf(fmaxf(v1, -1.f), 1.f);
  float sb = sqrtf(fmaxf(1.f - cb*cb, 0.f));
  float h = sqrtf(v0*v0 + v2*v2);
  float ca, sa;
  if (h > 1e-20f) { float ih = 1.f/h; ca = v2*ih; sa = v0*ih; }
  else            { ca = 1.f; sa = 0.f; }

  {
    float Za[9] = {ca,0,sa, 0,1,0, -sa,0,ca};
    float Zb[9] = {cb,0,sb, 0,1,0, -sb,0,cb};
    const float J1[9] = {0,1,0, 1,0,0, 0,0,-1};
    float T[9], T2[9], D1[9];
    mm3(Zb, J1, T); mm3(J1, T, T2); mm3(Za, T2, D1);
#pragma unroll
    for (int i = 0; i < 9; ++i) D1buf[(size_t)e*9 + i] = D1[i];
  }
  {
    float c2a = ca*ca - sa*sa, s2a = 2.f*ca*sa;
    float c2b = cb*cb - sb*sb, s2b = 2.f*cb*sb;
    float Za2[25] = {
      c2a, 0,   0, 0,   s2a,
      0,   ca,  0, sa,  0,
      0,   0,   1, 0,   0,
      0,  -sa,  0, ca,  0,
     -s2a, 0,   0, 0,   c2a};
    float Zb2[25] = {
      c2b, 0,   0, 0,   s2b,
      0,   cb,  0, sb,  0,
      0,   0,   1, 0,   0,
      0,  -sb,  0, cb,  0,
     -s2b, 0,   0, 0,   c2b};
    const float S3 = 0.8660254037844386f;
    const float J2[25] = {
      0, 0, 0,    -1, 0,
      0, 1, 0,     0, 0,
      0, 0, -0.5f, 0, -S3,
     -1, 0, 0,     0, 0,
      0, 0, -S3,   0, 0.5f};
    float T[25], T2[25], D2[25];
    mm5(Zb2, J2, T); mm5(J2, T, T2); mm5(Za2, T2, D2);
#pragma unroll
    for (int i = 0; i < 25; ++i) D2buf[(size_t)e*25 + i] = D2[i];
  }
}

// Expand weights into dense per-m fp16 matrices (row-major N x K) + f32 bias.
__global__ __launch_bounds__(256) void build_mats(const float* __restrict__ W0,
                                                  const float* __restrict__ b0,
                                                  const float* __restrict__ W1,
                                                  const float* __restrict__ W2,
                                                  _Float16* __restrict__ M0,
                                                  float* __restrict__ B0,
                                                  _Float16* __restrict__ M1,
                                                  _Float16* __restrict__ M2) {
  int i = blockIdx.x*256 + threadIdx.x;
  if (i < 98304) {                       // M0: 384 x 256 = W0[:,128:384]
    int k = i >> 8, j = i & 255;
    M0[i] = (_Float16)W0[k*384 + 128 + j];
  } else if (i < 98688) {                // B0: 384 (f32)
    B0[i - 98304] = b0[i - 98304];
  } else if (i < 360832) {               // M1: 512 x 512 = [[Wa,-Wb],[Wb,Wa]]
    int idx = i - 98688;
    int k = idx >> 9, j = idx & 511;
    float val;
    if (k < 256) val = (j < 256) ? W1[k*256 + j] : -W1[(k+256)*256 + (j-256)];
    else         val = (j < 256) ? W1[k*256 + j] :  W1[(k-256)*256 + (j-256)];
    M1[idx] = (_Float16)val;
  } else if (i < 426368) {               // M2: 256 x 256 = [[Wa,-Wb],[Wb,Wa]]
    int idx = i - 360832;
    int k = idx >> 8, j = idx & 255;
    float val;
    if (k < 128) val = (j < 128) ? W2[k*128 + j] : -W2[(k+128)*128 + (j-128)];
    else         val = (j < 128) ? W2[k*128 + j] :  W2[(k-128)*128 + (j-128)];
    M2[idx] = (_Float16)val;
  }
}

// One wave per edge: rotate by D^T, gather into fp16 U row (1024).
__global__ __launch_bounds__(256) void rotate_gather(const float* __restrict__ x,
                                                     const float* __restrict__ D1buf,
                                                     const float* __restrict__ D2buf,
                                                     _Float16* __restrict__ U, int n) {
  __shared__ float xs[4][1152];
  __shared__ __align__(16) _Float16 us16[4][1024];
  const int w = threadIdx.x >> 6;
  const int lane = threadIdx.x & 63;
  const int e = blockIdx.x*4 + w;

  const float4* xr = (const float4*)(x + (size_t)e*1152);
  float4* xsw = (float4*)xs[w];
#pragma unroll
  for (int i = 0; i < 4; ++i) xsw[lane + i*64] = xr[lane + i*64];
  if (lane < 32) xsw[lane + 256] = xr[lane + 256];

  float d1[9], d2[25];
#pragma unroll
  for (int i = 0; i < 9; ++i) d1[i] = D1buf[(size_t)e*9 + i];
#pragma unroll
  for (int i = 0; i < 25; ++i) d2[i] = D2buf[(size_t)e*25 + i];

  __syncthreads();

#pragma unroll
  for (int hh = 0; hh < 2; ++hh) {
    int c = lane + 64*hh;
    // l=1: r = D1^T b
    float b0 = xs[w][128 + 3*c + 0];
    float b1 = xs[w][128 + 3*c + 1];
    float b2 = xs[w][128 + 3*c + 2];
    float r0 = fmaf(d1[0], b0, fmaf(d1[3], b1, d1[6]*b2));
    float r1 = fmaf(d1[1], b0, fmaf(d1[4], b1, d1[7]*b2));
    float r2 = fmaf(d1[2], b0, fmaf(d1[5], b1, d1[8]*b2));
    us16[w][c] = (_Float16)r1;                         // l1 mid
    { f16x2 t; t[0] = (_Float16)r0; t[1] = (_Float16)r2;
      *(f16x2*)&us16[w][256 + 2*c] = t; }              // l1 m1 pair

    // l=2: rr = D2^T q
    float q0 = xs[w][512 + 5*c + 0];
    float q1 = xs[w][512 + 5*c + 1];
    float q2 = xs[w][512 + 5*c + 2];
    float q3 = xs[w][512 + 5*c + 3];
    float q4 = xs[w][512 + 5*c + 4];
    float rr[5];
#pragma unroll
    for (int i = 0; i < 5; ++i)
      rr[i] = fmaf(d2[0*5+i], q0, fmaf(d2[1*5+i], q1, fmaf(d2[2*5+i], q2,
               fmaf(d2[3*5+i], q3, d2[4*5+i]*q4))));
    us16[w][128 + c] = (_Float16)rr[2];                // l2 mid
    { f16x2 t; t[0] = (_Float16)rr[1]; t[1] = (_Float16)rr[3];
      *(f16x2*)&us16[w][512 + 2*c] = t; }              // l2 m1 pair
    { f16x2 t; t[0] = (_Float16)rr[0]; t[1] = (_Float16)rr[4];
      if (c < 64) *(f16x2*)&us16[w][768 + 2*c] = t;    // l2 m2 ch0-63
      else        *(f16x2*)&us16[w][896 + 2*(c-64)] = t; }
  }
  __syncthreads();

  f16x8* Ur = (f16x8*)(U + (size_t)e*1024);
  const f16x8* usw = (const f16x8*)us16[w];
#pragma unroll
  for (int i = 0; i < 2; ++i) Ur[i*64 + lane] = usw[i*64 + lane];
}

// fp16 MFMA GEMM: C section = A[n x K] @ M^T (+bias) into packed V (d_out).
// 128x128 tile, BK=64, 4 waves (2x2), 4x4 16x16x32 fragments per wave.
// LDS staged via global_load_lds w16 with pre-swizzled source (s' = s ^ (r&7)).
__global__ __launch_bounds__(256) void gemm_mfma(const _Float16* __restrict__ U,
                                                 const _Float16* __restrict__ M0,
                                                 const float* __restrict__ B0,
                                                 const _Float16* __restrict__ M1,
                                                 const _Float16* __restrict__ M2,
                                                 float* __restrict__ C, int n) {
  const int y = blockIdx.y;
  int K, Aoff, Coff, colTile;
  const _Float16* Mp;
  const float* bias = nullptr;
  if (y < 3)      { K = 256; Aoff = 0;   Coff = 0;   colTile = y;     Mp = M0; bias = B0; }
  else if (y < 7) { K = 512; Aoff = 256; Coff = 384; colTile = y - 3; Mp = M1; }
  else            { K = 256; Aoff = 768; Coff = 896; colTile = y - 7; Mp = M2; }
  const int colBase = colTile * 128;
  const int rowBase = blockIdx.x * 128;

  __shared__ __align__(16) _Float16 Als[128*64];   // 16 KB, [row][64K], seg-swizzled
  __shared__ __align__(16) _Float16 Bls[128*64];   // 16 KB, [col][64K], seg-swizzled

  const int t  = threadIdx.x;
  const int w  = t >> 6, l = t & 63;
  const int wr = w >> 1, wc = w & 1;
  const int fr = l & 15, g0 = l >> 4;

  const char* Ag = (const char*)(U + (size_t)rowBase*1024 + Aoff);
  const char* Bg = (const char*)(Mp + (size_t)colBase*K);
  // staging: LDS byte q = c*1024 + l*16 -> row r=c*8+(l>>3), seg s=l&7.
  // source segment s' = s ^ (r&7) = (l&7) ^ (l>>3)  (c*8 == 0 mod 8).
  const int sprime = (l & 7) ^ (l >> 3);
  const int rl = l >> 3;

  f32x4 acc[4][4];
#pragma unroll
  for (int m = 0; m < 4; ++m)
#pragma unroll
    for (int nn = 0; nn < 4; ++nn) { f32x4 z = {0.f,0.f,0.f,0.f}; acc[m][nn] = z; }

  for (int kk = 0; kk < K; kk += 64) {
#pragma unroll
    for (int cc = 0; cc < 4; ++cc) {
      const int c = w + cc*4;                     // chunk 0..15 (1 KB each)
      const int r = c*8 + rl;
      __builtin_amdgcn_global_load_lds(
          (const AS1 void*)(Ag + (size_t)r*2048 + (size_t)kk*2 + sprime*16),
          (AS3 void*)((char*)Als + c*1024), 16, 0, 0);
      __builtin_amdgcn_global_load_lds(
          (const AS1 void*)(Bg + (size_t)r*(size_t)(K*2) + (size_t)kk*2 + sprime*16),
          (AS3 void*)((char*)Bls + c*1024), 16, 0, 0);
    }
    __syncthreads();   // compiler drains vmcnt before barrier

#pragma unroll
    for (int h = 0; h < 2; ++h) {
      const int sidx = h*4 + g0;                  // K-seg (8 elems) 0..7
      f16x8 af[4], bf[4];
#pragma unroll
      for (int m = 0; m < 4; ++m) {
        const int row = wr*64 + m*16 + fr;
        af[m] = *(const f16x8*)((const char*)Als + row*128 + ((sidx ^ (row & 7))*16));
      }
#pragma unroll
      for (int nn = 0; nn < 4; ++nn) {
        const int col = wc*64 + nn*16 + fr;
        bf[nn] = *(const f16x8*)((const char*)Bls + col*128 + ((sidx ^ (col & 7))*16));
      }
#pragma unroll
      for (int m = 0; m < 4; ++m)
#pragma unroll
        for (int nn = 0; nn < 4; ++nn)
          acc[m][nn] = __builtin_amdgcn_mfma_f32_16x16x32_f16(af[m], bf[nn], acc[m][nn], 0, 0, 0);
    }
    __syncthreads();
  }

  // epilogue: C/D layout col=l&15, row=(l>>4)*4+j  [m89-verified, dtype-indep]
  float bv[4];
#pragma unroll
  for (int nn = 0; nn < 4; ++nn)
    bv[nn] = bias ? bias[colBase + wc*64 + nn*16 + fr] : 0.f;
#pragma unroll
  for (int m = 0; m < 4; ++m) {
    const int row0 = rowBase + wr*64 + m*16 + g0*4;
#pragma unroll
    for (int nn = 0; nn < 4; ++nn) {
      const int vc = Coff + colBase + wc*64 + nn*16 + fr;
#pragma unroll
      for (int j = 0; j < 4; ++j)
        C[(size_t)(row0 + j)*1152 + vc] = acc[m][nn][j] + bv[nn];
    }
  }
}

// One wave per edge: packed V row -> rotate by D -> final layout. In-place d_out.
__global__ __launch_bounds__(256) void rotate_back(float* __restrict__ out,
                                                   const float* __restrict__ D1buf,
                                                   const float* __restrict__ D2buf, int n) {
  __shared__ float vs[4][1152];
  __shared__ float fs[4][1152];
  const int w = threadIdx.x >> 6;
  const int lane = threadIdx.x & 63;
  const int e = blockIdx.x*4 + w;

  const float4* vr = (const float4*)(out + (size_t)e*1152);
  float4* vsw = (float4*)vs[w];
#pragma unroll
  for (int i = 0; i < 4; ++i) vsw[lane + i*64] = vr[lane + i*64];
  if (lane < 32) vsw[lane + 256] = vr[lane + 256];

  float d1[9], d2[25];
#pragma unroll
  for (int i = 0; i < 9; ++i) d1[i] = D1buf[(size_t)e*9 + i];
#pragma unroll
  for (int i = 0; i < 25; ++i) d2[i] = D2buf[(size_t)e*25 + i];

  __syncthreads();

  fs[w][lane]      = vs[w][lane];
  fs[w][64 + lane] = vs[w][64 + lane];

#pragma unroll
  for (int hh = 0; hh < 2; ++hh) {
    int c = lane + 64*hh;
    float p0 = vs[w][384 + 2*c];
    float p1 = vs[w][128 + c];
    float p2 = vs[w][384 + 2*c + 1];
    fs[w][128 + 3*c + 0] = fmaf(d1[0], p0, fmaf(d1[1], p1, d1[2]*p2));
    fs[w][128 + 3*c + 1] = fmaf(d1[3], p0, fmaf(d1[4], p1, d1[5]*p2));
    fs[w][128 + 3*c + 2] = fmaf(d1[6], p0, fmaf(d1[7], p1, d1[8]*p2));

    float q0, q4;
    if (c < 64) { q0 = vs[w][896 + 2*c];        q4 = vs[w][896 + 2*c + 1]; }
    else        { q0 = vs[w][1024 + 2*(c-64)];  q4 = vs[w][1024 + 2*(c-64) + 1]; }
    float q1 = vs[w][640 + 2*c];
    float q2 = vs[w][256 + c];
    float q3 = vs[w][640 + 2*c + 1];
#pragma unroll
    for (int i = 0; i < 5; ++i)
      fs[w][512 + 5*c + i] = fmaf(d2[i*5+0], q0, fmaf(d2[i*5+1], q1, fmaf(d2[i*5+2], q2,
                              fmaf(d2[i*5+3], q3, d2[i*5+4]*q4))));
  }
  __syncthreads();

  float4* orow = (float4*)(out + (size_t)e*1152);
  const float4* fsw = (const float4*)fs[w];
#pragma unroll
  for (int i = 0; i < 4; ++i) orow[lane + i*64] = fsw[lane + i*64];
  if (lane < 32) orow[lane + 256] = fsw[lane + 256];
}

extern "C" void kernel_launch(void* const* d_in, const int* in_sizes, int n_in,
                              void* d_out, int out_size, void* d_ws, size_t ws_size,
                              hipStream_t stream) {
  const float* x  = (const float*)d_in[0];
  const float* R  = (const float*)d_in[1];
  const float* W0 = (const float*)d_in[2];
  const float* b0 = (const float*)d_in[3];
  const float* W1 = (const float*)d_in[4];
  const float* W2 = (const float*)d_in[5];
  float* out = (float*)d_out;

  const int n = in_sizes[0] / 1152;   // 32768

  // workspace layout (bytes, all 16B-aligned)
  char* wsb = (char*)d_ws;
  _Float16* U16  = (_Float16*)wsb;                          // n*1024*2   = 64 MB
  float* D1buf   = (float*)(wsb + (size_t)n*1024*2);        // n*9*4
  float* D2buf   = D1buf + (size_t)n*9;                     // n*25*4
  _Float16* M0h  = (_Float16*)(D2buf + (size_t)n*25);       // 98304*2
  _Float16* M1h  = M0h + 98304;                             // 262144*2
  _Float16* M2h  = M1h + 262144;                            // 65536*2
  float* B0f     = (float*)(M2h + 65536);                   // 384*4

  wigner_k<<<(n + 255)/256, 256, 0, stream>>>(R, D1buf, D2buf, n);
  build_mats<<<(426368 + 255)/256, 256, 0, stream>>>(W0, b0, W1, W2, M0h, B0f, M1h, M2h);
  rotate_gather<<<n/4, 256, 0, stream>>>(x, D1buf, D2buf, U16, n);
  dim3 ggrid(n/128, 9);
  gemm_mfma<<<ggrid, 256, 0, stream>>>(U16, M0h, B0f, M1h, M2h, out, n);
  rotate_back<<<n/4, 256, 0, stream>>>(out, D1buf, D2buf, n);
}

// Round 5
// 367.765 us; speedup vs baseline: 1.7327x; 1.0432x over previous
//
#include <hip/hip_runtime.h>
#include <cstddef>
#include <cstdint>

// ---------------------------------------------------------------------------
// SO2_Linear r5: LDS-free rotate kernels + XCD-aware GEMM grid (A L2 reuse).
//   1. wigner_k       : per-edge D1 (3x3), D2 (5x5) -> ws (f32)
//   2. build_mats     : W0/W1/W2 -> fp16 M0(384x256), M1(512x512), M2(256x256)
//   3. rotate_gather  : thread-per-(edge,channel), x -> D^T-rotated fp16 U
//   4. gemm_mfma      : 16x16x32 f16 MFMA, 128x128 tile, swizzled LDS stage,
//                       1D grid ordered so a row-tile's 9 sections share an XCD
//   5. rotate_back    : thread-per-(edge,channel), V(ws,f32) -> D-rotated d_out
//      (fallback: V in d_out + r4's in-place LDS rotate_back if ws too small)
// ---------------------------------------------------------------------------

typedef _Float16 f16x8 __attribute__((ext_vector_type(8)));
typedef _Float16 f16x2 __attribute__((ext_vector_type(2)));
typedef float    f32x4 __attribute__((ext_vector_type(4)));

#define AS1 __attribute__((address_space(1)))
#define AS3 __attribute__((address_space(3)))

__device__ __forceinline__ void mm3(const float* A, const float* B, float* C) {
#pragma unroll
  for (int i = 0; i < 3; ++i)
#pragma unroll
    for (int j = 0; j < 3; ++j)
      C[i*3+j] = fmaf(A[i*3+0], B[0*3+j], fmaf(A[i*3+1], B[1*3+j], A[i*3+2]*B[2*3+j]));
}

__device__ __forceinline__ void mm5(const float* A, const float* B, float* C) {
#pragma unroll
  for (int i = 0; i < 5; ++i)
#pragma unroll
    for (int j = 0; j < 5; ++j) {
      float s = 0.f;
#pragma unroll
      for (int k = 0; k < 5; ++k) s = fmaf(A[i*5+k], B[k*5+j], s);
      C[i*5+j] = s;
    }
}

__global__ __launch_bounds__(256) void wigner_k(const float* __restrict__ R,
                                                float* __restrict__ D1buf,
                                                float* __restrict__ D2buf, int n) {
  int e = blockIdx.x*256 + threadIdx.x;
  if (e >= n) return;
  float r0 = R[3*e+0], r1 = R[3*e+1], r2 = R[3*e+2];
  float v0 = r1, v1 = r2, v2 = r0;          // v = R[[1,2,0]]
  float nrm = fmaxf(sqrtf(v0*v0 + v1*v1 + v2*v2), 1e-12f);
  float inv = 1.0f/nrm;
  v0 *= inv; v1 *= inv; v2 *= inv;

  float cb = fminf(fmaxf(v1, -1.f), 1.f);
  float sb = sqrtf(fmaxf(1.f - cb*cb, 0.f));
  float h = sqrtf(v0*v0 + v2*v2);
  float ca, sa;
  if (h > 1e-20f) { float ih = 1.f/h; ca = v2*ih; sa = v0*ih; }
  else            { ca = 1.f; sa = 0.f; }

  {
    float Za[9] = {ca,0,sa, 0,1,0, -sa,0,ca};
    float Zb[9] = {cb,0,sb, 0,1,0, -sb,0,cb};
    const float J1[9] = {0,1,0, 1,0,0, 0,0,-1};
    float T[9], T2[9], D1[9];
    mm3(Zb, J1, T); mm3(J1, T, T2); mm3(Za, T2, D1);
#pragma unroll
    for (int i = 0; i < 9; ++i) D1buf[(size_t)e*9 + i] = D1[i];
  }
  {
    float c2a = ca*ca - sa*sa, s2a = 2.f*ca*sa;
    float c2b = cb*cb - sb*sb, s2b = 2.f*cb*sb;
    float Za2[25] = {
      c2a, 0,   0, 0,   s2a,
      0,   ca,  0, sa,  0,
      0,   0,   1, 0,   0,
      0,  -sa,  0, ca,  0,
     -s2a, 0,   0, 0,   c2a};
    float Zb2[25] = {
      c2b, 0,   0, 0,   s2b,
      0,   cb,  0, sb,  0,
      0,   0,   1, 0,   0,
      0,  -sb,  0, cb,  0,
     -s2b, 0,   0, 0,   c2b};
    const float S3 = 0.8660254037844386f;
    const float J2[25] = {
      0, 0, 0,    -1, 0,
      0, 1, 0,     0, 0,
      0, 0, -0.5f, 0, -S3,
     -1, 0, 0,     0, 0,
      0, 0, -S3,   0, 0.5f};
    float T[25], T2[25], D2[25];
    mm5(Zb2, J2, T); mm5(J2, T, T2); mm5(Za2, T2, D2);
#pragma unroll
    for (int i = 0; i < 25; ++i) D2buf[(size_t)e*25 + i] = D2[i];
  }
}

__global__ __launch_bounds__(256) void build_mats(const float* __restrict__ W0,
                                                  const float* __restrict__ b0,
                                                  const float* __restrict__ W1,
                                                  const float* __restrict__ W2,
                                                  _Float16* __restrict__ M0,
                                                  float* __restrict__ B0,
                                                  _Float16* __restrict__ M1,
                                                  _Float16* __restrict__ M2) {
  int i = blockIdx.x*256 + threadIdx.x;
  if (i < 98304) {                       // M0: 384 x 256 = W0[:,128:384]
    int k = i >> 8, j = i & 255;
    M0[i] = (_Float16)W0[k*384 + 128 + j];
  } else if (i < 98688) {                // B0: 384 (f32)
    B0[i - 98304] = b0[i - 98304];
  } else if (i < 360832) {               // M1: 512 x 512 = [[Wa,-Wb],[Wb,Wa]]
    int idx = i - 98688;
    int k = idx >> 9, j = idx & 511;
    float val;
    if (k < 256) val = (j < 256) ? W1[k*256 + j] : -W1[(k+256)*256 + (j-256)];
    else         val = (j < 256) ? W1[k*256 + j] :  W1[(k-256)*256 + (j-256)];
    M1[idx] = (_Float16)val;
  } else if (i < 426368) {               // M2: 256 x 256 = [[Wa,-Wb],[Wb,Wa]]
    int idx = i - 360832;
    int k = idx >> 8, j = idx & 255;
    float val;
    if (k < 128) val = (j < 128) ? W2[k*128 + j] : -W2[(k+128)*128 + (j-128)];
    else         val = (j < 128) ? W2[k*128 + j] :  W2[(k-128)*128 + (j-128)];
    M2[idx] = (_Float16)val;
  }
}

// LDS-free: one thread per (edge, channel). Wave covers 64 consecutive channels
// of ONE edge (tid>>7 = edge) -> all global accesses wave-contiguous; D loads
// wave-uniform (cache broadcast).
__global__ __launch_bounds__(256) void rotate_gather(const float* __restrict__ x,
                                                     const float* __restrict__ D1buf,
                                                     const float* __restrict__ D2buf,
                                                     _Float16* __restrict__ U, int n) {
  const int tid = blockIdx.x*256 + threadIdx.x;
  const int e = tid >> 7;
  const int c = tid & 127;
  if (e >= n) return;

  float d1[9], d2[25];
#pragma unroll
  for (int i = 0; i < 9; ++i) d1[i] = D1buf[(size_t)e*9 + i];
#pragma unroll
  for (int i = 0; i < 25; ++i) d2[i] = D2buf[(size_t)e*25 + i];

  const float* xr = x + (size_t)e*1152;
  _Float16* Ur = U + (size_t)e*1024;

  // l=1: r = D1^T b
  float b0 = xr[128 + 3*c + 0];
  float b1 = xr[128 + 3*c + 1];
  float b2 = xr[128 + 3*c + 2];
  float r0 = fmaf(d1[0], b0, fmaf(d1[3], b1, d1[6]*b2));
  float r1 = fmaf(d1[1], b0, fmaf(d1[4], b1, d1[7]*b2));
  float r2 = fmaf(d1[2], b0, fmaf(d1[5], b1, d1[8]*b2));
  Ur[c] = (_Float16)r1;                              // l1 mid
  { f16x2 t; t[0] = (_Float16)r0; t[1] = (_Float16)r2;
    *(f16x2*)&Ur[256 + 2*c] = t; }                   // l1 m1 pair

  // l=2: rr = D2^T q
  float q0 = xr[512 + 5*c + 0];
  float q1 = xr[512 + 5*c + 1];
  float q2 = xr[512 + 5*c + 2];
  float q3 = xr[512 + 5*c + 3];
  float q4 = xr[512 + 5*c + 4];
  float rr[5];
#pragma unroll
  for (int i = 0; i < 5; ++i)
    rr[i] = fmaf(d2[0*5+i], q0, fmaf(d2[1*5+i], q1, fmaf(d2[2*5+i], q2,
             fmaf(d2[3*5+i], q3, d2[4*5+i]*q4))));
  Ur[128 + c] = (_Float16)rr[2];                     // l2 mid
  { f16x2 t; t[0] = (_Float16)rr[1]; t[1] = (_Float16)rr[3];
    *(f16x2*)&Ur[512 + 2*c] = t; }                   // l2 m1 pair
  { f16x2 t; t[0] = (_Float16)rr[0]; t[1] = (_Float16)rr[4];
    if (c < 64) *(f16x2*)&Ur[768 + 2*c] = t;         // l2 m2 ch0-63
    else        *(f16x2*)&Ur[896 + 2*(c-64)] = t; }
}

// fp16 MFMA GEMM: V section = A[n x K] @ M^T (+bias) into packed V (f32).
// 1D grid ordered so the 9 sections of one row-tile are consecutive on one XCD
// (bid = ((rr*9 + sec)<<3) | x8, rowTile = rr*8 + x8) -> A tile L2-resident.
__global__ __launch_bounds__(256) void gemm_mfma(const _Float16* __restrict__ U,
                                                 const _Float16* __restrict__ M0,
                                                 const float* __restrict__ B0,
                                                 const _Float16* __restrict__ M1,
                                                 const _Float16* __restrict__ M2,
                                                 float* __restrict__ C, int n) {
  const int bid = blockIdx.x;
  const int x8 = bid & 7;
  const int g  = bid >> 3;
  const int rr = g / 9;
  const int sec = g - rr*9;
  const int rowBase = (rr*8 + x8) * 128;

  int K, Aoff, Coff, colTile;
  const _Float16* Mp;
  const float* bias = nullptr;
  if (sec < 3)      { K = 256; Aoff = 0;   Coff = 0;   colTile = sec;     Mp = M0; bias = B0; }
  else if (sec < 7) { K = 512; Aoff = 256; Coff = 384; colTile = sec - 3; Mp = M1; }
  else              { K = 256; Aoff = 768; Coff = 896; colTile = sec - 7; Mp = M2; }
  const int colBase = colTile * 128;

  __shared__ __align__(16) _Float16 Als[128*64];   // 16 KB, [row][64K], seg-swizzled
  __shared__ __align__(16) _Float16 Bls[128*64];   // 16 KB, [col][64K], seg-swizzled

  const int t  = threadIdx.x;
  const int w  = t >> 6, l = t & 63;
  const int wr = w >> 1, wc = w & 1;
  const int fr = l & 15, g0 = l >> 4;

  const char* Ag = (const char*)(U + (size_t)rowBase*1024 + Aoff);
  const char* Bg = (const char*)(Mp + (size_t)colBase*K);
  // staging: LDS byte q = c*1024 + l*16 -> row r=c*8+(l>>3), seg s=l&7.
  // source segment s' = s ^ (r&7) = (l&7) ^ (l>>3).
  const int sprime = (l & 7) ^ (l >> 3);
  const int rl = l >> 3;

  f32x4 acc[4][4];
#pragma unroll
  for (int m = 0; m < 4; ++m)
#pragma unroll
    for (int nn = 0; nn < 4; ++nn) { f32x4 z = {0.f,0.f,0.f,0.f}; acc[m][nn] = z; }

  for (int kk = 0; kk < K; kk += 64) {
#pragma unroll
    for (int cc = 0; cc < 4; ++cc) {
      const int c = w + cc*4;                     // chunk 0..15 (1 KB each)
      const int r = c*8 + rl;
      __builtin_amdgcn_global_load_lds(
          (const AS1 void*)(Ag + (size_t)r*2048 + (size_t)kk*2 + sprime*16),
          (AS3 void*)((char*)Als + c*1024), 16, 0, 0);
      __builtin_amdgcn_global_load_lds(
          (const AS1 void*)(Bg + (size_t)r*(size_t)(K*2) + (size_t)kk*2 + sprime*16),
          (AS3 void*)((char*)Bls + c*1024), 16, 0, 0);
    }
    __syncthreads();

#pragma unroll
    for (int h = 0; h < 2; ++h) {
      const int sidx = h*4 + g0;                  // K-seg (8 elems) 0..7
      f16x8 af[4], bf[4];
#pragma unroll
      for (int m = 0; m < 4; ++m) {
        const int row = wr*64 + m*16 + fr;
        af[m] = *(const f16x8*)((const char*)Als + row*128 + ((sidx ^ (row & 7))*16));
      }
#pragma unroll
      for (int nn = 0; nn < 4; ++nn) {
        const int col = wc*64 + nn*16 + fr;
        bf[nn] = *(const f16x8*)((const char*)Bls + col*128 + ((sidx ^ (col & 7))*16));
      }
#pragma unroll
      for (int m = 0; m < 4; ++m)
#pragma unroll
        for (int nn = 0; nn < 4; ++nn)
          acc[m][nn] = __builtin_amdgcn_mfma_f32_16x16x32_f16(af[m], bf[nn], acc[m][nn], 0, 0, 0);
    }
    __syncthreads();
  }

  // epilogue: C/D layout col=l&15, row=(l>>4)*4+j
  float bv[4];
#pragma unroll
  for (int nn = 0; nn < 4; ++nn)
    bv[nn] = bias ? bias[colBase + wc*64 + nn*16 + fr] : 0.f;
#pragma unroll
  for (int m = 0; m < 4; ++m) {
    const int row0 = rowBase + wr*64 + m*16 + g0*4;
#pragma unroll
    for (int nn = 0; nn < 4; ++nn) {
      const int vc = Coff + colBase + wc*64 + nn*16 + fr;
#pragma unroll
      for (int j = 0; j < 4; ++j)
        C[(size_t)(row0 + j)*1152 + vc] = acc[m][nn][j] + bv[nn];
    }
  }
}

// LDS-free rotate-back: V (f32, ws) -> final layout in d_out.
__global__ __launch_bounds__(256) void rotate_back2(const float* __restrict__ V,
                                                    float* __restrict__ out,
                                                    const float* __restrict__ D1buf,
                                                    const float* __restrict__ D2buf, int n) {
  const int tid = blockIdx.x*256 + threadIdx.x;
  const int e = tid >> 7;
  const int c = tid & 127;
  if (e >= n) return;

  float d1[9], d2[25];
#pragma unroll
  for (int i = 0; i < 9; ++i) d1[i] = D1buf[(size_t)e*9 + i];
#pragma unroll
  for (int i = 0; i < 25; ++i) d2[i] = D2buf[(size_t)e*25 + i];

  const float* Vr = V + (size_t)e*1152;
  float* orow = out + (size_t)e*1152;

  // l=0 passthrough
  orow[c] = Vr[c];

  // l=1: vec = [m1-minus, mid, m1-plus]; o_i = sum_j D1[i,j] p_j
  float2 pp = *(const float2*)&Vr[384 + 2*c];
  float p0 = pp.x, p2 = pp.y;
  float p1 = Vr[128 + c];
  orow[128 + 3*c + 0] = fmaf(d1[0], p0, fmaf(d1[1], p1, d1[2]*p2));
  orow[128 + 3*c + 1] = fmaf(d1[3], p0, fmaf(d1[4], p1, d1[5]*p2));
  orow[128 + 3*c + 2] = fmaf(d1[6], p0, fmaf(d1[7], p1, d1[8]*p2));

  // l=2: vec = [m2-minus, m1-minus, mid, m1-plus, m2-plus]
  float2 qq = (c < 64) ? *(const float2*)&Vr[896 + 2*c]
                       : *(const float2*)&Vr[1024 + 2*(c-64)];
  float q0 = qq.x, q4 = qq.y;
  float2 q13 = *(const float2*)&Vr[640 + 2*c];
  float q1 = q13.x, q3 = q13.y;
  float q2 = Vr[256 + c];
#pragma unroll
  for (int i = 0; i < 5; ++i)
    orow[512 + 5*c + i] = fmaf(d2[i*5+0], q0, fmaf(d2[i*5+1], q1, fmaf(d2[i*5+2], q2,
                           fmaf(d2[i*5+3], q3, d2[i*5+4]*q4))));
}

// Fallback (verified r4): in-place LDS-staged rotate-back on d_out.
__global__ __launch_bounds__(256) void rotate_back_ip(float* __restrict__ out,
                                                      const float* __restrict__ D1buf,
                                                      const float* __restrict__ D2buf, int n) {
  __shared__ float vs[4][1152];
  __shared__ float fs[4][1152];
  const int w = threadIdx.x >> 6;
  const int lane = threadIdx.x & 63;
  const int e = blockIdx.x*4 + w;

  const float4* vr = (const float4*)(out + (size_t)e*1152);
  float4* vsw = (float4*)vs[w];
#pragma unroll
  for (int i = 0; i < 4; ++i) vsw[lane + i*64] = vr[lane + i*64];
  if (lane < 32) vsw[lane + 256] = vr[lane + 256];

  float d1[9], d2[25];
#pragma unroll
  for (int i = 0; i < 9; ++i) d1[i] = D1buf[(size_t)e*9 + i];
#pragma unroll
  for (int i = 0; i < 25; ++i) d2[i] = D2buf[(size_t)e*25 + i];

  __syncthreads();

  fs[w][lane]      = vs[w][lane];
  fs[w][64 + lane] = vs[w][64 + lane];

#pragma unroll
  for (int hh = 0; hh < 2; ++hh) {
    int c = lane + 64*hh;
    float p0 = vs[w][384 + 2*c];
    float p1 = vs[w][128 + c];
    float p2 = vs[w][384 + 2*c + 1];
    fs[w][128 + 3*c + 0] = fmaf(d1[0], p0, fmaf(d1[1], p1, d1[2]*p2));
    fs[w][128 + 3*c + 1] = fmaf(d1[3], p0, fmaf(d1[4], p1, d1[5]*p2));
    fs[w][128 + 3*c + 2] = fmaf(d1[6], p0, fmaf(d1[7], p1, d1[8]*p2));

    float q0, q4;
    if (c < 64) { q0 = vs[w][896 + 2*c];        q4 = vs[w][896 + 2*c + 1]; }
    else        { q0 = vs[w][1024 + 2*(c-64)];  q4 = vs[w][1024 + 2*(c-64) + 1]; }
    float q1 = vs[w][640 + 2*c];
    float q2 = vs[w][256 + c];
    float q3 = vs[w][640 + 2*c + 1];
#pragma unroll
    for (int i = 0; i < 5; ++i)
      fs[w][512 + 5*c + i] = fmaf(d2[i*5+0], q0, fmaf(d2[i*5+1], q1, fmaf(d2[i*5+2], q2,
                              fmaf(d2[i*5+3], q3, d2[i*5+4]*q4))));
  }
  __syncthreads();

  float4* orow = (float4*)(out + (size_t)e*1152);
  const float4* fsw = (const float4*)fs[w];
#pragma unroll
  for (int i = 0; i < 4; ++i) orow[lane + i*64] = fsw[lane + i*64];
  if (lane < 32) orow[lane + 256] = fsw[lane + 256];
}

extern "C" void kernel_launch(void* const* d_in, const int* in_sizes, int n_in,
                              void* d_out, int out_size, void* d_ws, size_t ws_size,
                              hipStream_t stream) {
  const float* x  = (const float*)d_in[0];
  const float* R  = (const float*)d_in[1];
  const float* W0 = (const float*)d_in[2];
  const float* b0 = (const float*)d_in[3];
  const float* W1 = (const float*)d_in[4];
  const float* W2 = (const float*)d_in[5];
  float* out = (float*)d_out;

  const int n = in_sizes[0] / 1152;   // 32768

  // ws layout (bytes, all 16B-aligned)
  const size_t szV  = (size_t)n*1152*4;   // 151 MB (optional)
  const size_t szU  = (size_t)n*1024*2;   // 64 MB
  const size_t szD1 = (size_t)n*9*4;
  const size_t szD2 = (size_t)n*25*4;
  const size_t szM  = 196608 + 524288 + 131072 + 1536;
  const bool vInWs = ws_size >= szV + szU + szD1 + szD2 + szM;

  char* p = (char*)d_ws;
  float* V32 = nullptr;
  if (vInWs) { V32 = (float*)p; p += szV; }
  _Float16* U16 = (_Float16*)p;            p += szU;
  float* D1buf  = (float*)p;               p += szD1;
  float* D2buf  = (float*)p;               p += szD2;
  _Float16* M0h = (_Float16*)p;            p += 196608;
  _Float16* M1h = (_Float16*)p;            p += 524288;
  _Float16* M2h = (_Float16*)p;            p += 131072;
  float* B0f    = (float*)p;

  wigner_k<<<(n + 255)/256, 256, 0, stream>>>(R, D1buf, D2buf, n);
  build_mats<<<(426368 + 255)/256, 256, 0, stream>>>(W0, b0, W1, W2, M0h, B0f, M1h, M2h);
  rotate_gather<<<n/2, 256, 0, stream>>>(x, D1buf, D2buf, U16, n);

  float* V = vInWs ? V32 : out;
  gemm_mfma<<<(n/128)*9, 256, 0, stream>>>(U16, M0h, B0f, M1h, M2h, V, n);

  if (vInWs) rotate_back2<<<n/2, 256, 0, stream>>>(V32, out, D1buf, D2buf, n);
  else       rotate_back_ip<<<n/4, 256, 0, stream>>>(out, D1buf, D2buf, n);
}

// Round 6
// 346.281 us; speedup vs baseline: 1.8403x; 1.0620x over previous
//
#include <hip/hip_runtime.h>
#include <cstddef>
#include <cstdint>

// ---------------------------------------------------------------------------
// SO2_Linear r6: V in fp16 (halves V round-trip traffic vs r5).
//   1. wigner_k       : per-edge D1 (3x3), D2 (5x5) -> ws (f32)
//   2. build_mats     : W0/W1/W2 -> fp16 M0(384x256), M1(512x512), M2(256x256)
//   3. rotate_gather  : thread-per-(edge,channel), x -> D^T-rotated fp16 U
//   4. gemm_mfma      : 16x16x32 f16 MFMA, 128x128 tile, swizzled LDS stage,
//                       XCD-aware 1D grid; output packed V in fp16 -> ws
//   5. rotate_back2   : thread-per-(edge,channel), V(f16) -> D-rotated f32 out
// ---------------------------------------------------------------------------

typedef _Float16 f16x8 __attribute__((ext_vector_type(8)));
typedef _Float16 f16x2 __attribute__((ext_vector_type(2)));
typedef float    f32x4 __attribute__((ext_vector_type(4)));

#define AS1 __attribute__((address_space(1)))
#define AS3 __attribute__((address_space(3)))

__device__ __forceinline__ void mm3(const float* A, const float* B, float* C) {
#pragma unroll
  for (int i = 0; i < 3; ++i)
#pragma unroll
    for (int j = 0; j < 3; ++j)
      C[i*3+j] = fmaf(A[i*3+0], B[0*3+j], fmaf(A[i*3+1], B[1*3+j], A[i*3+2]*B[2*3+j]));
}

__device__ __forceinline__ void mm5(const float* A, const float* B, float* C) {
#pragma unroll
  for (int i = 0; i < 5; ++i)
#pragma unroll
    for (int j = 0; j < 5; ++j) {
      float s = 0.f;
#pragma unroll
      for (int k = 0; k < 5; ++k) s = fmaf(A[i*5+k], B[k*5+j], s);
      C[i*5+j] = s;
    }
}

__global__ __launch_bounds__(256) void wigner_k(const float* __restrict__ R,
                                                float* __restrict__ D1buf,
                                                float* __restrict__ D2buf, int n) {
  int e = blockIdx.x*256 + threadIdx.x;
  if (e >= n) return;
  float r0 = R[3*e+0], r1 = R[3*e+1], r2 = R[3*e+2];
  float v0 = r1, v1 = r2, v2 = r0;          // v = R[[1,2,0]]
  float nrm = fmaxf(sqrtf(v0*v0 + v1*v1 + v2*v2), 1e-12f);
  float inv = 1.0f/nrm;
  v0 *= inv; v1 *= inv; v2 *= inv;

  float cb = fminf(fmaxf(v1, -1.f), 1.f);
  float sb = sqrtf(fmaxf(1.f - cb*cb, 0.f));
  float h = sqrtf(v0*v0 + v2*v2);
  float ca, sa;
  if (h > 1e-20f) { float ih = 1.f/h; ca = v2*ih; sa = v0*ih; }
  else            { ca = 1.f; sa = 0.f; }

  {
    float Za[9] = {ca,0,sa, 0,1,0, -sa,0,ca};
    float Zb[9] = {cb,0,sb, 0,1,0, -sb,0,cb};
    const float J1[9] = {0,1,0, 1,0,0, 0,0,-1};
    float T[9], T2[9], D1[9];
    mm3(Zb, J1, T); mm3(J1, T, T2); mm3(Za, T2, D1);
#pragma unroll
    for (int i = 0; i < 9; ++i) D1buf[(size_t)e*9 + i] = D1[i];
  }
  {
    float c2a = ca*ca - sa*sa, s2a = 2.f*ca*sa;
    float c2b = cb*cb - sb*sb, s2b = 2.f*cb*sb;
    float Za2[25] = {
      c2a, 0,   0, 0,   s2a,
      0,   ca,  0, sa,  0,
      0,   0,   1, 0,   0,
      0,  -sa,  0, ca,  0,
     -s2a, 0,   0, 0,   c2a};
    float Zb2[25] = {
      c2b, 0,   0, 0,   s2b,
      0,   cb,  0, sb,  0,
      0,   0,   1, 0,   0,
      0,  -sb,  0, cb,  0,
     -s2b, 0,   0, 0,   c2b};
    const float S3 = 0.8660254037844386f;
    const float J2[25] = {
      0, 0, 0,    -1, 0,
      0, 1, 0,     0, 0,
      0, 0, -0.5f, 0, -S3,
     -1, 0, 0,     0, 0,
      0, 0, -S3,   0, 0.5f};
    float T[25], T2[25], D2[25];
    mm5(Zb2, J2, T); mm5(J2, T, T2); mm5(Za2, T2, D2);
#pragma unroll
    for (int i = 0; i < 25; ++i) D2buf[(size_t)e*25 + i] = D2[i];
  }
}

__global__ __launch_bounds__(256) void build_mats(const float* __restrict__ W0,
                                                  const float* __restrict__ b0,
                                                  const float* __restrict__ W1,
                                                  const float* __restrict__ W2,
                                                  _Float16* __restrict__ M0,
                                                  float* __restrict__ B0,
                                                  _Float16* __restrict__ M1,
                                                  _Float16* __restrict__ M2) {
  int i = blockIdx.x*256 + threadIdx.x;
  if (i < 98304) {                       // M0: 384 x 256 = W0[:,128:384]
    int k = i >> 8, j = i & 255;
    M0[i] = (_Float16)W0[k*384 + 128 + j];
  } else if (i < 98688) {                // B0: 384 (f32)
    B0[i - 98304] = b0[i - 98304];
  } else if (i < 360832) {               // M1: 512 x 512 = [[Wa,-Wb],[Wb,Wa]]
    int idx = i - 98688;
    int k = idx >> 9, j = idx & 511;
    float val;
    if (k < 256) val = (j < 256) ? W1[k*256 + j] : -W1[(k+256)*256 + (j-256)];
    else         val = (j < 256) ? W1[k*256 + j] :  W1[(k-256)*256 + (j-256)];
    M1[idx] = (_Float16)val;
  } else if (i < 426368) {               // M2: 256 x 256 = [[Wa,-Wb],[Wb,Wa]]
    int idx = i - 360832;
    int k = idx >> 8, j = idx & 255;
    float val;
    if (k < 128) val = (j < 128) ? W2[k*128 + j] : -W2[(k+128)*128 + (j-128)];
    else         val = (j < 128) ? W2[k*128 + j] :  W2[(k-128)*128 + (j-128)];
    M2[idx] = (_Float16)val;
  }
}

// LDS-free: one thread per (edge, channel); wave = 64 channels of one edge.
__global__ __launch_bounds__(256) void rotate_gather(const float* __restrict__ x,
                                                     const float* __restrict__ D1buf,
                                                     const float* __restrict__ D2buf,
                                                     _Float16* __restrict__ U, int n) {
  const int tid = blockIdx.x*256 + threadIdx.x;
  const int e = tid >> 7;
  const int c = tid & 127;
  if (e >= n) return;

  float d1[9], d2[25];
#pragma unroll
  for (int i = 0; i < 9; ++i) d1[i] = D1buf[(size_t)e*9 + i];
#pragma unroll
  for (int i = 0; i < 25; ++i) d2[i] = D2buf[(size_t)e*25 + i];

  const float* xr = x + (size_t)e*1152;
  _Float16* Ur = U + (size_t)e*1024;

  // l=1: r = D1^T b
  float b0 = xr[128 + 3*c + 0];
  float b1 = xr[128 + 3*c + 1];
  float b2 = xr[128 + 3*c + 2];
  float r0 = fmaf(d1[0], b0, fmaf(d1[3], b1, d1[6]*b2));
  float r1 = fmaf(d1[1], b0, fmaf(d1[4], b1, d1[7]*b2));
  float r2 = fmaf(d1[2], b0, fmaf(d1[5], b1, d1[8]*b2));
  Ur[c] = (_Float16)r1;                              // l1 mid
  { f16x2 t; t[0] = (_Float16)r0; t[1] = (_Float16)r2;
    *(f16x2*)&Ur[256 + 2*c] = t; }                   // l1 m1 pair

  // l=2: rr = D2^T q
  float q0 = xr[512 + 5*c + 0];
  float q1 = xr[512 + 5*c + 1];
  float q2 = xr[512 + 5*c + 2];
  float q3 = xr[512 + 5*c + 3];
  float q4 = xr[512 + 5*c + 4];
  float rr[5];
#pragma unroll
  for (int i = 0; i < 5; ++i)
    rr[i] = fmaf(d2[0*5+i], q0, fmaf(d2[1*5+i], q1, fmaf(d2[2*5+i], q2,
             fmaf(d2[3*5+i], q3, d2[4*5+i]*q4))));
  Ur[128 + c] = (_Float16)rr[2];                     // l2 mid
  { f16x2 t; t[0] = (_Float16)rr[1]; t[1] = (_Float16)rr[3];
    *(f16x2*)&Ur[512 + 2*c] = t; }                   // l2 m1 pair
  { f16x2 t; t[0] = (_Float16)rr[0]; t[1] = (_Float16)rr[4];
    if (c < 64) *(f16x2*)&Ur[768 + 2*c] = t;         // l2 m2 ch0-63
    else        *(f16x2*)&Ur[896 + 2*(c-64)] = t; }
}

// fp16 MFMA GEMM: V section = A[n x K] @ M^T (+bias), output packed V in fp16.
// 1D grid: bid = ((rr*9+sec)<<3)|x8, rowTile = rr*8+x8 -> a row-tile's 9
// sections are consecutive on one XCD (A-tile L2-resident).
__global__ __launch_bounds__(256) void gemm_mfma(const _Float16* __restrict__ U,
                                                 const _Float16* __restrict__ M0,
                                                 const float* __restrict__ B0,
                                                 const _Float16* __restrict__ M1,
                                                 const _Float16* __restrict__ M2,
                                                 _Float16* __restrict__ C, int n) {
  const int bid = blockIdx.x;
  const int x8 = bid & 7;
  const int g  = bid >> 3;
  const int rr = g / 9;
  const int sec = g - rr*9;
  const int rowBase = (rr*8 + x8) * 128;

  int K, Aoff, Coff, colTile;
  const _Float16* Mp;
  const float* bias = nullptr;
  if (sec < 3)      { K = 256; Aoff = 0;   Coff = 0;   colTile = sec;     Mp = M0; bias = B0; }
  else if (sec < 7) { K = 512; Aoff = 256; Coff = 384; colTile = sec - 3; Mp = M1; }
  else              { K = 256; Aoff = 768; Coff = 896; colTile = sec - 7; Mp = M2; }
  const int colBase = colTile * 128;

  __shared__ __align__(16) _Float16 Als[128*64];   // 16 KB, [row][64K], seg-swizzled
  __shared__ __align__(16) _Float16 Bls[128*64];   // 16 KB, [col][64K], seg-swizzled

  const int t  = threadIdx.x;
  const int w  = t >> 6, l = t & 63;
  const int wr = w >> 1, wc = w & 1;
  const int fr = l & 15, g0 = l >> 4;

  const char* Ag = (const char*)(U + (size_t)rowBase*1024 + Aoff);
  const char* Bg = (const char*)(Mp + (size_t)colBase*K);
  // staging: LDS byte q = c*1024 + l*16 -> row r=c*8+(l>>3), seg s=l&7.
  // source segment s' = s ^ (r&7) = (l&7) ^ (l>>3).
  const int sprime = (l & 7) ^ (l >> 3);
  const int rl = l >> 3;

  f32x4 acc[4][4];
#pragma unroll
  for (int m = 0; m < 4; ++m)
#pragma unroll
    for (int nn = 0; nn < 4; ++nn) { f32x4 z = {0.f,0.f,0.f,0.f}; acc[m][nn] = z; }

  for (int kk = 0; kk < K; kk += 64) {
#pragma unroll
    for (int cc = 0; cc < 4; ++cc) {
      const int c = w + cc*4;                     // chunk 0..15 (1 KB each)
      const int r = c*8 + rl;
      __builtin_amdgcn_global_load_lds(
          (const AS1 void*)(Ag + (size_t)r*2048 + (size_t)kk*2 + sprime*16),
          (AS3 void*)((char*)Als + c*1024), 16, 0, 0);
      __builtin_amdgcn_global_load_lds(
          (const AS1 void*)(Bg + (size_t)r*(size_t)(K*2) + (size_t)kk*2 + sprime*16),
          (AS3 void*)((char*)Bls + c*1024), 16, 0, 0);
    }
    __syncthreads();

#pragma unroll
    for (int h = 0; h < 2; ++h) {
      const int sidx = h*4 + g0;                  // K-seg (8 elems) 0..7
      f16x8 af[4], bf[4];
#pragma unroll
      for (int m = 0; m < 4; ++m) {
        const int row = wr*64 + m*16 + fr;
        af[m] = *(const f16x8*)((const char*)Als + row*128 + ((sidx ^ (row & 7))*16));
      }
#pragma unroll
      for (int nn = 0; nn < 4; ++nn) {
        const int col = wc*64 + nn*16 + fr;
        bf[nn] = *(const f16x8*)((const char*)Bls + col*128 + ((sidx ^ (col & 7))*16));
      }
#pragma unroll
      for (int m = 0; m < 4; ++m)
#pragma unroll
        for (int nn = 0; nn < 4; ++nn)
          acc[m][nn] = __builtin_amdgcn_mfma_f32_16x16x32_f16(af[m], bf[nn], acc[m][nn], 0, 0, 0);
    }
    __syncthreads();
  }

  // epilogue: C/D layout col=l&15, row=(l>>4)*4+j; cast to f16 on store
  float bv[4];
#pragma unroll
  for (int nn = 0; nn < 4; ++nn)
    bv[nn] = bias ? bias[colBase + wc*64 + nn*16 + fr] : 0.f;
#pragma unroll
  for (int m = 0; m < 4; ++m) {
    const int row0 = rowBase + wr*64 + m*16 + g0*4;
#pragma unroll
    for (int nn = 0; nn < 4; ++nn) {
      const int vc = Coff + colBase + wc*64 + nn*16 + fr;
#pragma unroll
      for (int j = 0; j < 4; ++j)
        C[(size_t)(row0 + j)*1152 + vc] = (_Float16)(acc[m][nn][j] + bv[nn]);
    }
  }
}

// LDS-free rotate-back: V (f16, ws) -> final f32 layout in d_out.
__global__ __launch_bounds__(256) void rotate_back2(const _Float16* __restrict__ V,
                                                    float* __restrict__ out,
                                                    const float* __restrict__ D1buf,
                                                    const float* __restrict__ D2buf, int n) {
  const int tid = blockIdx.x*256 + threadIdx.x;
  const int e = tid >> 7;
  const int c = tid & 127;
  if (e >= n) return;

  float d1[9], d2[25];
#pragma unroll
  for (int i = 0; i < 9; ++i) d1[i] = D1buf[(size_t)e*9 + i];
#pragma unroll
  for (int i = 0; i < 25; ++i) d2[i] = D2buf[(size_t)e*25 + i];

  const _Float16* Vr = V + (size_t)e*1152;
  float* orow = out + (size_t)e*1152;

  // l=0 passthrough
  orow[c] = (float)Vr[c];

  // l=1: vec = [m1-minus, mid, m1-plus]; o_i = sum_j D1[i,j] p_j
  f16x2 pp = *(const f16x2*)&Vr[384 + 2*c];
  float p0 = (float)pp[0], p2 = (float)pp[1];
  float p1 = (float)Vr[128 + c];
  orow[128 + 3*c + 0] = fmaf(d1[0], p0, fmaf(d1[1], p1, d1[2]*p2));
  orow[128 + 3*c + 1] = fmaf(d1[3], p0, fmaf(d1[4], p1, d1[5]*p2));
  orow[128 + 3*c + 2] = fmaf(d1[6], p0, fmaf(d1[7], p1, d1[8]*p2));

  // l=2: vec = [m2-minus, m1-minus, mid, m1-plus, m2-plus]
  f16x2 qq = (c < 64) ? *(const f16x2*)&Vr[896 + 2*c]
                      : *(const f16x2*)&Vr[1024 + 2*(c-64)];
  float q0 = (float)qq[0], q4 = (float)qq[1];
  f16x2 q13 = *(const f16x2*)&Vr[640 + 2*c];
  float q1 = (float)q13[0], q3 = (float)q13[1];
  float q2 = (float)Vr[256 + c];
#pragma unroll
  for (int i = 0; i < 5; ++i)
    orow[512 + 5*c + i] = fmaf(d2[i*5+0], q0, fmaf(d2[i*5+1], q1, fmaf(d2[i*5+2], q2,
                           fmaf(d2[i*5+3], q3, d2[i*5+4]*q4))));
}

extern "C" void kernel_launch(void* const* d_in, const int* in_sizes, int n_in,
                              void* d_out, int out_size, void* d_ws, size_t ws_size,
                              hipStream_t stream) {
  const float* x  = (const float*)d_in[0];
  const float* R  = (const float*)d_in[1];
  const float* W0 = (const float*)d_in[2];
  const float* b0 = (const float*)d_in[3];
  const float* W1 = (const float*)d_in[4];
  const float* W2 = (const float*)d_in[5];
  float* out = (float*)d_out;

  const int n = in_sizes[0] / 1152;   // 32768

  // ws layout (bytes, all 16B-aligned); total ~145 MB of the 576 MiB ws
  char* p = (char*)d_ws;
  _Float16* V16 = (_Float16*)p;  p += (size_t)n*1152*2;   // 75.5 MB
  _Float16* U16 = (_Float16*)p;  p += (size_t)n*1024*2;   // 64 MB
  float* D1buf  = (float*)p;     p += (size_t)n*9*4;
  float* D2buf  = (float*)p;     p += (size_t)n*25*4;
  _Float16* M0h = (_Float16*)p;  p += 196608;
  _Float16* M1h = (_Float16*)p;  p += 524288;
  _Float16* M2h = (_Float16*)p;  p += 131072;
  float* B0f    = (float*)p;

  wigner_k<<<(n + 255)/256, 256, 0, stream>>>(R, D1buf, D2buf, n);
  build_mats<<<(426368 + 255)/256, 256, 0, stream>>>(W0, b0, W1, W2, M0h, B0f, M1h, M2h);
  rotate_gather<<<n/2, 256, 0, stream>>>(x, D1buf, D2buf, U16, n);
  gemm_mfma<<<(n/128)*9, 256, 0, stream>>>(U16, M0h, B0f, M1h, M2h, V16, n);
  rotate_back2<<<n/2, 256, 0, stream>>>(V16, out, D1buf, D2buf, n);
}